// Round 1
// baseline (457.480 us; speedup 1.0000x reference)
//
#include <hip/hip_runtime.h>
#include <hip/hip_bf16.h>

#define KT    16
#define NPER  16384
#define DIN   256
#define DOUT  256
#define NTOT  (KT * NPER)

typedef __attribute__((ext_vector_type(8))) short  short8;
typedef __attribute__((ext_vector_type(4))) float  f32x4;
typedef __attribute__((ext_vector_type(4))) unsigned int uint32x4;

// fp32 -> bf16 round-to-nearest-even (bit twiddle; no NaN in this data)
__device__ __forceinline__ unsigned short f2bf(float f) {
    unsigned int u = __float_as_uint(f);
    u += 0x7fffu + ((u >> 16) & 1u);
    return (unsigned short)(u >> 16);
}

// tanh(y) = sign(y) * (1 - t) / (1 + t),  t = exp(-2|y|)  (stable, no overflow)
__device__ __forceinline__ float fast_tanh(float y) {
    float a = fabsf(y);
    float t = __expf(-2.0f * a);
    float r = (1.0f - t) * __builtin_amdgcn_rcpf(1.0f + t);
    return copysignf(r, y);
}

// ---- prep kernels -----------------------------------------------------------

__global__ void prep_w(const float* __restrict__ w, unsigned short* __restrict__ wbf) {
    int i = blockIdx.x * blockDim.x + threadIdx.x;    // 262144 float4 groups
    float4 v = ((const float4*)w)[i];
    unsigned int p0 = (unsigned int)f2bf(v.x) | ((unsigned int)f2bf(v.y) << 16);
    unsigned int p1 = (unsigned int)f2bf(v.z) | ((unsigned int)f2bf(v.w) << 16);
    ((uint2*)wbf)[i] = make_uint2(p0, p1);
}

__global__ void prep_inv(const int* __restrict__ perm, int* __restrict__ inv) {
    int i = blockIdx.x * blockDim.x + threadIdx.x;    // NTOT threads
    inv[perm[i]] = i;
}

// ---- main GEMM + scatter + tanh --------------------------------------------
// Block tile: BM=128 rows x BN=256 cols (full D_OUT), BK=64, 4 K-stages.
// 512 threads = 8 waves, each wave computes 64x64 (4x4 grid of 16x16x32 mfma).
// LDS rows padded to 72 bf16 (144 B) -> 2-way bank aliasing (free on CDNA4).

__launch_bounds__(512, 4)
__global__ void gemm_scatter(const float* __restrict__ x,
                             const unsigned short* __restrict__ wbf,
                             const int* __restrict__ inv,
                             float* __restrict__ out) {
    __shared__ unsigned short aLds[128 * 72];   // 18 KiB
    __shared__ unsigned short bLds[256 * 72];   // 36 KiB
    __shared__ int invLds[128];

    const int tid = threadIdx.x;
    const int bid = blockIdx.x;
    const int kt  = bid >> 7;          // 16 types
    const int rt  = bid & 127;         // 128 row tiles per type

    const float*          xblk = x   + (size_t)(kt * NPER + rt * 128) * DIN;
    const unsigned short* wblk = wbf + (size_t)kt * DOUT * DIN;

    if (tid < 128) invLds[tid] = inv[kt * NPER + rt * 128 + tid];

    const int lane = tid & 63;
    const int wv   = tid >> 6;     // 0..7
    const int wm   = wv & 1;       // row half (0..1)
    const int wn   = wv >> 1;      // col quarter (0..3)
    const int lo   = lane & 15;
    const int hi   = lane >> 4;

    f32x4 acc[4][4];
#pragma unroll
    for (int i = 0; i < 4; i++)
#pragma unroll
        for (int j = 0; j < 4; j++) acc[i][j] = (f32x4){0.f, 0.f, 0.f, 0.f};

    for (int s = 0; s < 4; ++s) {
        const int d0 = s * 64;

        // stage A: 128 rows x 64 fp32 -> bf16.  1024 chunks of 8 floats.
#pragma unroll
        for (int r8 = 0; r8 < 2; r8++) {
            int idx = tid + r8 * 512;
            int row = idx >> 3, c8 = idx & 7;
            const float4* p = (const float4*)(xblk + row * DIN + d0 + c8 * 8);
            float4 v0 = p[0];
            float4 v1 = p[1];
            uint32x4 pk;
            pk.x = (unsigned int)f2bf(v0.x) | ((unsigned int)f2bf(v0.y) << 16);
            pk.y = (unsigned int)f2bf(v0.z) | ((unsigned int)f2bf(v0.w) << 16);
            pk.z = (unsigned int)f2bf(v1.x) | ((unsigned int)f2bf(v1.y) << 16);
            pk.w = (unsigned int)f2bf(v1.z) | ((unsigned int)f2bf(v1.w) << 16);
            *(uint32x4*)&aLds[row * 72 + c8 * 8] = pk;
        }
        // stage B: 256 rows x 64 bf16.  2048 chunks of 8 bf16 (16 B).
#pragma unroll
        for (int r8 = 0; r8 < 4; r8++) {
            int idx = tid + r8 * 512;
            int row = idx >> 3, c8 = idx & 7;
            uint32x4 v = *(const uint32x4*)(wblk + row * DIN + d0 + c8 * 8);
            *(uint32x4*)&bLds[row * 72 + c8 * 8] = v;
        }
        __syncthreads();

#pragma unroll
        for (int ks = 0; ks < 2; ++ks) {
            const int k0 = ks * 32;
            short8 af[4], bfr[4];
#pragma unroll
            for (int i = 0; i < 4; i++)
                af[i] = *(const short8*)&aLds[(wm * 64 + i * 16 + lo) * 72 + k0 + hi * 8];
#pragma unroll
            for (int j = 0; j < 4; j++)
                bfr[j] = *(const short8*)&bLds[(wn * 64 + j * 16 + lo) * 72 + k0 + hi * 8];
#pragma unroll
            for (int i = 0; i < 4; i++)
#pragma unroll
                for (int j = 0; j < 4; j++)
                    acc[i][j] = __builtin_amdgcn_mfma_f32_16x16x32_bf16(
                        af[i], bfr[j], acc[i][j], 0, 0, 0);
        }
        __syncthreads();
    }

    // epilogue: tanh + permuted row scatter.
    // C/D layout: col = lane&15, row = (lane>>4)*4 + reg   [measured m89/m91]
#pragma unroll
    for (int i = 0; i < 4; i++) {
#pragma unroll
        for (int r = 0; r < 4; r++) {
            int rowL = wm * 64 + i * 16 + hi * 4 + r;
            size_t orow = (size_t)invLds[rowL];
            float* op = out + orow * DOUT;
#pragma unroll
            for (int j = 0; j < 4; j++) {
                int col = wn * 64 + j * 16 + lo;
                op[col] = fast_tanh(acc[i][j][r]);
            }
        }
    }
}

// ---- launch -----------------------------------------------------------------

extern "C" void kernel_launch(void* const* d_in, const int* in_sizes, int n_in,
                              void* d_out, int out_size, void* d_ws, size_t ws_size,
                              hipStream_t stream) {
    const float* x    = (const float*)d_in[0];   // [16,16384,256] fp32
    const float* w    = (const float*)d_in[1];   // [16,256,256]  fp32
    const int*   perm = (const int*)d_in[2];     // [262144]      int32
    float*       out  = (float*)d_out;           // [262144,256]  fp32

    unsigned short* wbf = (unsigned short*)d_ws;                       // 2 MiB
    int*            inv = (int*)((char*)d_ws + (size_t)2 * 1024 * 1024); // 1 MiB

    prep_w  <<<1024, 256, 0, stream>>>(w, wbf);      // 16*256*256/4 float4s
    prep_inv<<<1024, 256, 0, stream>>>(perm, inv);   // NTOT threads
    gemm_scatter<<<KT * 128, 512, 0, stream>>>(x, wbf, inv, out);
}